// Round 4
// baseline (663.858 us; speedup 1.0000x reference)
//
#include <hip/hip_runtime.h>
#include <hip/hip_bf16.h>

#define VOCAB 50000
#define DD 128
#define TT 512
#define BB 512
#define HH 100
#define NCLS 4
#define NT 25            // 16-wide permuted col tiles covering 4H=400 exactly
#define ROWS 4           // real batch rows per block
#define NBLK (BB/ROWS)   // 128 blocks
#define NTHREADS 512     // 8 waves
#define ZS 400           // z_lds row stride (f32, float4-aligned)

typedef short s16x8 __attribute__((ext_vector_type(8)));
typedef float f32x4 __attribute__((ext_vector_type(4)));

static __device__ __forceinline__ unsigned short f2b(float x) {
    __hip_bfloat16 h = __float2bfloat16(x);
    return __builtin_bit_cast(unsigned short, h);
}
static __device__ __forceinline__ float sigm(float x)  { return __fdividef(1.0f, 1.0f + __expf(-x)); }
static __device__ __forceinline__ float tanhx(float x) { return 1.0f - __fdividef(2.0f, 1.0f + __expf(2.0f * x)); }

// raw barrier: waits LDS ops only; global loads (vmcnt) stay in flight
#define BARRIER() asm volatile("s_waitcnt lgkmcnt(0)\n\ts_barrier" ::: "memory")

// ---------------- prep: cast embedding table f32 -> bf16 ----------------
__global__ void cast_emb_k(const float* __restrict__ emb, unsigned short* __restrict__ out, int n4) {
    int i = blockIdx.x * blockDim.x + threadIdx.x;
    if (i < n4) {
        float4 v = reinterpret_cast<const float4*>(emb)[i];
        ushort4 o = make_ushort4(f2b(v.x), f2b(v.y), f2b(v.z), f2b(v.w));
        reinterpret_cast<ushort4*>(out)[i] = o;
    }
}

// ---------------- prep: bake kernel & rec_kernel into per-lane MFMA B-fragments ----------------
// PERMUTED columns: dest col c' = j*4 + gate  <->  orig col = (c'&3)*100 + (c'>>2)
// frag(nt, ks), lane l, elem j <- M[k = ks*32 + (l>>4)*8 + j][orig_col(nt*16 + (l&15))]
__global__ void build_frags_k(const float* __restrict__ kern, const float* __restrict__ rec,
                              unsigned short* __restrict__ ikf, unsigned short* __restrict__ recf) {
    int tid = blockIdx.x * blockDim.x + threadIdx.x;
    if (tid >= 2 * NT * 4 * 64) return;
    int tab  = tid / (NT * 4 * 64);
    int rem  = tid % (NT * 4 * 64);
    int lane = rem & 63;
    int fs   = rem >> 6;
    int ks   = fs & 3, nt = fs >> 2;
    int cp    = nt * 16 + (lane & 15);           // permuted col
    int oc    = (cp & 3) * 100 + (cp >> 2);      // original col
    int kbase = ks * 32 + (lane >> 4) * 8;
    unsigned short* dst = (tab ? recf : ikf) + rem * 8;
#pragma unroll
    for (int j = 0; j < 8; ++j) {
        int k = kbase + j;
        float v;
        if (tab == 0) v = kern[k * 400 + oc];
        else          v = (k < HH) ? rec[k * 400 + oc] : 0.0f;
        dst[j] = f2b(v);
    }
}

// ---------------- fused LSTM: persistent, one barrier per step ----------------
__global__ __launch_bounds__(NTHREADS, 2)
void lstm_fused2_k(const int* __restrict__ tokens,
                   const float* __restrict__ bias,
                   const float* __restrict__ dw,
                   const float* __restrict__ db,
                   const unsigned short* __restrict__ emb_bf,
                   const unsigned short* __restrict__ ikf_tab,
                   const unsigned short* __restrict__ recf_tab,
                   float* __restrict__ out)
{
    __shared__ __align__(16) unsigned short h_lds[2][16 * DD]; // bf16 h double buffer, XOR-swizzled, rows 4..15 zero
    __shared__ float z_lds[ROWS][ZS];                          // permuted z, wave-private col ranges
    __shared__ float hf_lds[ROWS * HH];
    __shared__ float dw_lds[HH * NCLS];
    __shared__ int   tok_lds[ROWS][TT];

    const int tid = threadIdx.x, lane = tid & 63, w = tid >> 6;
    const int lo = lane & 15, hi = lane >> 4;
    const int b0 = blockIdx.x * ROWS;
    const int nt0 = (w * NT) >> 3;
    const int cnt = (((w + 1) * NT) >> 3) - nt0;   // 3 or 4 tiles per wave

    // weight fragments live in registers the whole kernel (~128 VGPR).
    // asm-pin after load: post-asm values are (to the compiler) not provably equal
    // to memory, so it cannot "spill" them by re-loading from L2 each step.
    s16x8 ikf[4][4], rcf[4][4];
    float bv[4];
#pragma unroll
    for (int i = 0; i < 4; ++i) {
        if (i < cnt) {
            int cp = (nt0 + i) * 16 + lo;
            bv[i] = bias[(cp & 3) * 100 + (cp >> 2)];
#pragma unroll
            for (int ks = 0; ks < 4; ++ks) {
                ikf[i][ks] = *reinterpret_cast<const s16x8*>(ikf_tab  + (((nt0 + i) * 4 + ks) * 64 + lane) * 8);
                rcf[i][ks] = *reinterpret_cast<const s16x8*>(recf_tab + (((nt0 + i) * 4 + ks) * 64 + lane) * 8);
            }
        } else {
            bv[i] = 0.0f;
#pragma unroll
            for (int ks = 0; ks < 4; ++ks) { ikf[i][ks] = (s16x8)0; rcf[i][ks] = (s16x8)0; }
        }
    }
#pragma unroll
    for (int i = 0; i < 4; ++i) {
        asm volatile("" : "+v"(bv[i]));
#pragma unroll
        for (int ks = 0; ks < 4; ++ks) {
            asm volatile("" : "+v"(ikf[i][ks]));
            asm volatile("" : "+v"(rcf[i][ks]));
        }
    }

    for (int idx = tid; idx < 16 * DD; idx += NTHREADS)   // zero both h buffers
        reinterpret_cast<unsigned int*>(&h_lds[0][0])[idx] = 0u;
    for (int idx = tid; idx < ROWS * TT; idx += NTHREADS)
        tok_lds[idx >> 9][idx & (TT - 1)] = tokens[(b0 + (idx >> 9)) * TT + (idx & (TT - 1))];
    if (tid < HH * NCLS) dw_lds[tid] = dw[tid];

    const int  grow = hi;                 // gate row 0..3
    const int  gjl  = lo;                 // gate j-local 0..15
    const bool g_on = gjl < 4 * cnt;      // all 64 lanes active when cnt==4
    float cst = 0.0f;

    const int xrow = lo & 3;              // A rows 4..15 duplicate rows 0..3 (pad C rows unused)
    int hof[4];
#pragma unroll
    for (int ks = 0; ks < 4; ++ks)
        hof[ks] = (lo * 256 + ks * 64 + hi * 16) ^ ((lo & 7) << 4);

    // x prefetch: 2-deep alternating buffers, loads land directly in freed buffer
    s16x8 xfA[4], xfB[4];
    {
        int t0 = tokens[(b0 + xrow) * TT + 0];
        int t1 = tokens[(b0 + xrow) * TT + 1];
#pragma unroll
        for (int ks = 0; ks < 4; ++ks) {
            xfA[ks] = *reinterpret_cast<const s16x8*>(emb_bf + (long)t0 * DD + ks * 32 + hi * 8);
            xfB[ks] = *reinterpret_cast<const s16x8*>(emb_bf + (long)t1 * DD + ks * 32 + hi * 8);
        }
    }
    __syncthreads();

    auto step = [&](int t, s16x8 (&xf)[4],
                    const unsigned short* hrd, unsigned short* hwr) {
        // h A-fragments from swizzled LDS (issue early; latency overlaps x-MFMAs)
        s16x8 hA[4];
#pragma unroll
        for (int ks = 0; ks < 4; ++ks)
            hA[ks] = *reinterpret_cast<const s16x8*>(reinterpret_cast<const char*>(hrd) + hof[ks]);

        f32x4 acc[4];
#pragma unroll
        for (int i = 0; i < 4; ++i) { acc[i][0] = bv[i]; acc[i][1] = bv[i]; acc[i][2] = bv[i]; acc[i][3] = bv[i]; }

        // x-part MFMAs (xf loaded 2 steps ago — vmcnt wait here, ~1000cy cover)
#pragma unroll
        for (int ks = 0; ks < 4; ++ks)
#pragma unroll
            for (int i = 0; i < 4; ++i)
                if (i < cnt) acc[i] = __builtin_amdgcn_mfma_f32_16x16x32_bf16(xf[ks], ikf[i][ks], acc[i], 0, 0, 0);

        // issue x prefetch for t+2 into the just-freed buffer (no copies)
        {
            int t2 = (t + 2 < TT) ? t + 2 : TT - 1;
            int tk = tok_lds[xrow][t2];
            const unsigned short* ep = emb_bf + (long)tk * DD;
#pragma unroll
            for (int ks = 0; ks < 4; ++ks)
                xf[ks] = *reinterpret_cast<const s16x8*>(ep + ks * 32 + hi * 8);
        }

        // h-part MFMAs
#pragma unroll
        for (int ks = 0; ks < 4; ++ks)
#pragma unroll
            for (int i = 0; i < 4; ++i)
                if (i < cnt) acc[i] = __builtin_amdgcn_mfma_f32_16x16x32_bf16(hA[ks], rcf[i][ks], acc[i], 0, 0, 0);

        // z write: real rows only (hi==0 lanes), wave-private col range -> no barrier
        if (hi == 0) {
#pragma unroll
            for (int i = 0; i < 4; ++i) if (i < cnt)
#pragma unroll
                for (int r = 0; r < 4; ++r)
                    z_lds[r][(nt0 + i) * 16 + lo] = acc[i][r];
        }

        // gates: read own wave's z (float4 = i,f,g,o thanks to permutation)
        if (g_on) {
            float4 z4 = *reinterpret_cast<const float4*>(&z_lds[grow][nt0 * 16 + gjl * 4]);
            float ig = sigm(z4.x), fg = sigm(z4.y), gg = tanhx(z4.z), og = sigm(z4.w);
            cst = fg * cst + ig * gg;
            float hh = og * tanhx(cst);
            int j = nt0 * 4 + gjl;
            *reinterpret_cast<unsigned short*>(reinterpret_cast<char*>(hwr) +
                ((grow * 256 + j * 2) ^ (grow << 4))) = f2b(hh);
            if (t == TT - 1) hf_lds[grow * HH + j] = hh;
        }
        BARRIER();
    };

    for (int t = 0; t < TT; t += 2) {
        step(t,     xfA, h_lds[1], h_lds[0]);   // read h_{t-1} from buf1, write h_t to buf0
        step(t + 1, xfB, h_lds[0], h_lds[1]);   // read buf0, write buf1
    }

    // epilogue: logits + softmax for this block's 4 rows
    if (tid < ROWS * NCLS) {
        int r = tid >> 2, c = tid & 3;
        float s = db[c];
#pragma unroll 4
        for (int k = 0; k < HH; ++k)
            s += hf_lds[r * HH + k] * dw_lds[k * NCLS + c];
        float mx = s;
        mx = fmaxf(mx, __shfl_xor(mx, 1));
        mx = fmaxf(mx, __shfl_xor(mx, 2));
        float e = __expf(s - mx);
        float den = e;
        den += __shfl_xor(den, 1);
        den += __shfl_xor(den, 2);
        out[(b0 + r) * NCLS + c] = e / den;
    }
}

extern "C" void kernel_launch(void* const* d_in, const int* in_sizes, int n_in,
                              void* d_out, int out_size, void* d_ws, size_t ws_size,
                              hipStream_t stream) {
    const int*   tokens = (const int*)d_in[0];
    const float* emb    = (const float*)d_in[1];
    const float* kern   = (const float*)d_in[2];
    const float* rec    = (const float*)d_in[3];
    const float* bias   = (const float*)d_in[4];
    const float* dw     = (const float*)d_in[5];
    const float* db     = (const float*)d_in[6];
    float* out = (float*)d_out;

    // ws layout: emb_bf16 (12.8MB) | ikf (100KB) | recf (100KB)
    unsigned short* emb_bf = (unsigned short*)d_ws;
    unsigned short* ikf    = emb_bf + (size_t)VOCAB * DD;
    unsigned short* recf   = ikf + NT * 4 * 64 * 8;

    int n4 = VOCAB * DD / 4;
    cast_emb_k<<<(n4 + 255) / 256, 256, 0, stream>>>(emb, emb_bf, n4);
    build_frags_k<<<(2 * NT * 4 * 64 + 255) / 256, 256, 0, stream>>>(kern, rec, ikf, recf);
    lstm_fused2_k<<<NBLK, NTHREADS, 0, stream>>>(tokens, bias, dw, db, emb_bf, ikf, recf, out);
}